// Round 8
// baseline (251.843 us; speedup 1.0000x reference)
//
#include <hip/hip_runtime.h>
#include <hip/hip_bf16.h>

#define B_ 4
#define S_ 2048
#define D_ 512
#define H_ 8
#define HD_ 64
#define M_TOT 8192  // B_*S_

typedef __attribute__((ext_vector_type(8))) short short8;
typedef __attribute__((ext_vector_type(4))) float f32x4;
typedef unsigned short u16;
typedef unsigned int u32;

__device__ __forceinline__ u16 f2bf(float f) {
  union { float f; u32 u; } v; v.f = f;
  u32 u = v.u;
  return (u16)((u + 0x7fffu + ((u >> 16) & 1u)) >> 16);  // RNE
}

// HW packed f32->bf16 (RNE), lo = src0, hi = src1
__device__ __forceinline__ u32 cvtpk(float lo, float hi) {
  u32 r;
  asm("v_cvt_pk_bf16_f32 %0, %1, %2" : "=v"(r) : "v"(lo), "v"(hi));
  return r;
}

__device__ __forceinline__ float exp2_hw(float x) { return __builtin_amdgcn_exp2f(x); }

__device__ __forceinline__ void gload16(const void* g, void* l) {
  // width-16 global->LDS DMA; LDS dest = wave-uniform base + lane*16
  __builtin_amdgcn_global_load_lds(
      (const __attribute__((address_space(1))) unsigned int*)g,
      (__attribute__((address_space(3))) unsigned int*)l, 16, 0, 0);
}

// ---------------------------------------------------------------- cast to bf16
__global__ __launch_bounds__(256) void cast_kernel(
    const float* __restrict__ x, const float* __restrict__ wq, const float* __restrict__ wk,
    const float* __restrict__ wv, const float* __restrict__ wo,
    u16* __restrict__ xb, u16* __restrict__ wqb, u16* __restrict__ wkb,
    u16* __restrict__ wvb, u16* __restrict__ wob)
{
  const int NX = M_TOT * D_ / 4;  // 1048576 float4s
  const int NW = D_ * D_ / 4;     // 65536
  int i = blockIdx.x * 256 + threadIdx.x;
  const float* src; u16* dst; int o;
  if (i < NX)               { src = x;  dst = xb;  o = i; }
  else if (i < NX + NW)     { src = wq; dst = wqb; o = i - NX; }
  else if (i < NX + 2 * NW) { src = wk; dst = wkb; o = i - NX - NW; }
  else if (i < NX + 3 * NW) { src = wv; dst = wvb; o = i - NX - 2 * NW; }
  else if (i < NX + 4 * NW) { src = wo; dst = wob; o = i - NX - 3 * NW; }
  else return;
  f32x4 v = ((const f32x4*)src)[o];
  u32 p0 = (u32)f2bf(v[0]) | ((u32)f2bf(v[1]) << 16);
  u32 p1 = (u32)f2bf(v[2]) | ((u32)f2bf(v[3]) << 16);
  u32* d = (u32*)(dst + (long)o * 4);
  d[0] = p0; d[1] = p1;
}

// ---------------------------------------------------------------- bf16 GEMM, B^T weights
// C[m][n] = sum_k A[m][k]*Bw[n][k] (+bias)
// mode 0 (fused QKV, N=1536): n<512 -> Q (scaled 0.125*log2e) [bh][s][hd]
//                             n<1024 -> K [bh][s][hd]
//                             else   -> V TRANSPOSED [bh][hd][s]
// mode 1 (out-proj, N=512): out_f32[m*D+n] = C + bias[n] + resid[m*D+n]
#define BM 128
#define BN 128
#define BKK 64

__global__ __launch_bounds__(256) void gemm_bt(
    const u16* __restrict__ A, const u16* __restrict__ Bw,
    const float* __restrict__ b0, const float* __restrict__ b1, const float* __restrict__ b2,
    const float* __restrict__ resid,
    u16* __restrict__ oq, u16* __restrict__ ok, u16* __restrict__ ov,
    float* __restrict__ out_f32, float qscale, int mode)
{
  __shared__ u16 As[BM * BKK];  // 16 KB, linear [row][128B] with XOR-swizzled contents
  __shared__ u16 Bs[BN * BKK];
  const int K = D_;
  const int tid = threadIdx.x;
  const int lane = tid & 63;
  const int wave = tid >> 6;
  const int wr = wave >> 1, wc = wave & 1;  // 2x2 waves, 64x64 each
  const int m0 = blockIdx.x * BM, n0 = blockIdx.y * BN;
  const int l15 = lane & 15, l4 = lane >> 4;

  f32x4 acc[4][4];
#pragma unroll
  for (int i = 0; i < 4; ++i)
#pragma unroll
    for (int j = 0; j < 4; ++j)
      acc[i][j] = (f32x4){0.f, 0.f, 0.f, 0.f};

  // staging geometry: per wave-inst, lane covers row (lane>>3), 16B chunk (lane&7)
  // LDS is LINEAR; the global SOURCE is inverse-swizzled (rule 21)
  const int srow_in_grp = lane >> 3;            // 0..7
  const int schunk = (lane & 7) * 16;           // byte chunk within 128B row
  const int ssw = srow_in_grp << 4;             // row-XOR
  const char* Ab = (const char*)(A + (long)m0 * K);
  const char* Bb = (const char*)(Bw + (long)n0 * K);

  for (int k0 = 0; k0 < K; k0 += BKK) {
    __syncthreads();  // prior tile's frag reads done
#pragma unroll
    for (int i = 0; i < 4; ++i) {
      int row = (wave * 4 + i) * 8 + srow_in_grp;
      long gsrc = (long)row * (K * 2) + k0 * 2 + (schunk ^ ssw);
      gload16(Ab + gsrc, (char*)As + (wave * 4 + i) * 1024);
      gload16(Bb + gsrc, (char*)Bs + (wave * 4 + i) * 1024);
    }
    __syncthreads();  // drains vmcnt(0): tiles resident

#pragma unroll
    for (int kb = 0; kb < 2; ++kb) {
      short8 af[4], bf[4];
      const int cb = kb * 64 + l4 * 16;  // byte col within row
#pragma unroll
      for (int i = 0; i < 4; ++i) {
        int ra = wr * 64 + i * 16 + l15;
        int rb = wc * 64 + i * 16 + l15;
        af[i] = *(const short8*)((const char*)As + ra * 128 + (cb ^ ((ra & 7) << 4)));
        bf[i] = *(const short8*)((const char*)Bs + rb * 128 + (cb ^ ((rb & 7) << 4)));
      }
#pragma unroll
      for (int i = 0; i < 4; ++i)
#pragma unroll
        for (int j = 0; j < 4; ++j)
          acc[i][j] = __builtin_amdgcn_mfma_f32_16x16x32_bf16(af[i], bf[j], acc[i][j], 0, 0, 0);
    }
  }

  if (mode == 0) {
    const int which = n0 >> 9;  // block-uniform: 0=Q,1=K,2=V
    const float* bias = which == 0 ? b0 : (which == 1 ? b1 : b2);
    const float scale = which == 0 ? qscale : 1.0f;
    u16* outp = which == 0 ? oq : (which == 1 ? ok : ov);
#pragma unroll
    for (int i = 0; i < 4; ++i) {
#pragma unroll
      for (int j = 0; j < 4; ++j) {
        int n = n0 + wc * 64 + j * 16 + l15;
        int nn = n & 511;
        float bv = bias[nn];
        int h = nn >> 6, hd = nn & 63;
        int mbase = m0 + wr * 64 + i * 16 + l4 * 4;
        int b = mbase >> 11, s0 = mbase & 2047;
        if (which == 2) {
          // V^T: [bh][hd][s]; 4 consecutive s -> one 8B store
          union { u16 u[4]; unsigned long long ll; } pk;
#pragma unroll
          for (int r = 0; r < 4; ++r)
            pk.u[r] = f2bf(acc[i][j][r] + bv);
          *(unsigned long long*)&outp[((long)(b * H_ + h) * HD_ + hd) * S_ + s0] = pk.ll;
        } else {
#pragma unroll
          for (int r = 0; r < 4; ++r) {
            float v = (acc[i][j][r] + bv) * scale;
            outp[((long)(b * H_ + h) * S_ + s0 + r) * HD_ + hd] = f2bf(v);
          }
        }
      }
    }
  } else {
#pragma unroll
    for (int i = 0; i < 4; ++i) {
#pragma unroll
      for (int j = 0; j < 4; ++j) {
        int n = n0 + wc * 64 + j * 16 + l15;
        float bv = b0[n];
#pragma unroll
        for (int r = 0; r < 4; ++r) {
          int m = m0 + wr * 64 + i * 16 + l4 * 4 + r;
          long idx = (long)m * D_ + n;
          out_f32[idx] = acc[i][j][r] + bv + resid[idx];
        }
      }
    }
  }
}

// ---------------------------------------------------------------- flash attention
// Q pre-scaled by 0.125*log2e -> softmax runs in exp2 domain. K [bh][s][hd],
// Vt [bh][hd][s]. TQ=64 (4 waves x 16 q-rows), TK=64, double-buffered
// global_load_lds staging (rule 21 swizzle), defer-max rescale (THR=8, T13),
// P->bf16 via v_cvt_pk_bf16_f32.
__global__ __launch_bounds__(256) void attn_kernel(
    const u16* __restrict__ Qg, const u16* __restrict__ Kg,
    const u16* __restrict__ Vtg, u16* __restrict__ ctx)
{
  __shared__ char Ks[2][8192];  // [kv 64][d 128B], XOR-swizzled contents
  __shared__ char Vs[2][8192];  // [d 64][kv 128B], XOR-swizzled contents
  __shared__ char Ps[8192];     // [q 64][kv 128B], wave-private rows, swizzled

  const int tid = threadIdx.x, lane = tid & 63, wave = tid >> 6;
  const int l15 = lane & 15, l4 = lane >> 4;
  const int lin = blockIdx.x;
  const int wg = (lin & 7) * 128 + (lin >> 3);  // XCD-chunked swizzle (1024 = 8*128)
  const int bh = wg >> 5;                       // 32 q-tiles per (b,h)
  const int q0 = (wg & 31) * 64;
  const int b = bh >> 3, h = bh & 7;
  const long hoff = (long)bh * S_ * HD_;
  const u16* Qh = Qg + hoff;
  const char* Kb = (const char*)(Kg + hoff);
  const char* Vb = (const char*)(Vtg + hoff);
  const int wrow = wave * 16;

  // staging geometry (per lane): row-in-inst = lane>>3, 16B chunk = lane&7
  const int srow = lane >> 3;
  const int soff = ((lane & 7) * 16) ^ (srow << 4);  // pre-swizzled byte in 128B window

  // Q fragments held in registers for the whole K/V sweep
  short8 qf[2];
#pragma unroll
  for (int kb = 0; kb < 2; ++kb)
    qf[kb] = *(const short8*)&Qh[(long)(q0 + wrow + l15) * HD_ + kb * 32 + l4 * 8];

  float mst[4], lst[4];
  f32x4 oacc[4];
#pragma unroll
  for (int r = 0; r < 4; ++r) { mst[r] = -1e30f; lst[r] = 0.f; }
#pragma unroll
  for (int nf = 0; nf < 4; ++nf)
    oacc[nf] = (f32x4){0.f, 0.f, 0.f, 0.f};

  // ---- prologue: stage tile 0
#pragma unroll
  for (int j = 0; j < 2; ++j) {
    int r = wrow + j * 8 + srow;
    gload16(Kb + (long)r * 128 + soff, Ks[0] + (wave * 2 + j) * 1024);
    gload16(Vb + (long)r * 4096 + soff, Vs[0] + (wave * 2 + j) * 1024);
  }
  __syncthreads();

  for (int t = 0; t < S_ / 64; ++t) {
    const int cur = t & 1;
    // ---- issue next tile's staging (in flight during compute)
    if (t < S_ / 64 - 1) {
      const int kv1 = (t + 1) * 64;
#pragma unroll
      for (int j = 0; j < 2; ++j) {
        int r = wrow + j * 8 + srow;
        gload16(Kb + (long)(kv1 + r) * 128 + soff, Ks[cur ^ 1] + (wave * 2 + j) * 1024);
        gload16(Vb + (long)r * 4096 + (long)kv1 * 2 + soff, Vs[cur ^ 1] + (wave * 2 + j) * 1024);
      }
    }

    // ---- S = Q @ K^T (log2-scaled)
    f32x4 sacc[4];
#pragma unroll
    for (int nf = 0; nf < 4; ++nf)
      sacc[nf] = (f32x4){0.f, 0.f, 0.f, 0.f};
#pragma unroll
    for (int kb = 0; kb < 2; ++kb) {
      const int cb = kb * 64 + l4 * 16;
      short8 kf[4];
#pragma unroll
      for (int nf = 0; nf < 4; ++nf) {
        int row = nf * 16 + l15;
        kf[nf] = *(const short8*)(Ks[cur] + row * 128 + (cb ^ ((row & 7) << 4)));
      }
#pragma unroll
      for (int nf = 0; nf < 4; ++nf)
        sacc[nf] = __builtin_amdgcn_mfma_f32_16x16x32_bf16(qf[kb], kf[nf], sacc[nf], 0, 0, 0);
    }

    // ---- online softmax, exp2 domain, defer-max (THR=8)
    float mx[4];
#pragma unroll
    for (int r = 0; r < 4; ++r) {
      float m = fmaxf(fmaxf(sacc[0][r], sacc[1][r]), fmaxf(sacc[2][r], sacc[3][r]));
      m = fmaxf(m, __shfl_xor(m, 1));
      m = fmaxf(m, __shfl_xor(m, 2));
      m = fmaxf(m, __shfl_xor(m, 4));
      m = fmaxf(m, __shfl_xor(m, 8));
      mx[r] = m;
    }
    int need = 0;
#pragma unroll
    for (int r = 0; r < 4; ++r) need |= (mx[r] > mst[r] + 8.0f) ? 1 : 0;
    if (__any(need)) {  // wave-uniform rescale (skipped on most tiles)
#pragma unroll
      for (int r = 0; r < 4; ++r) {
        float mnew = fmaxf(mst[r], mx[r]);
        float rs = exp2_hw(mst[r] - mnew);
        mst[r] = mnew;
        lst[r] *= rs;
#pragma unroll
        for (int nf = 0; nf < 4; ++nf)
          oacc[nf][r] *= rs;
      }
    }
#pragma unroll
    for (int r = 0; r < 4; ++r) {
      float rsum = 0.f;
#pragma unroll
      for (int nf = 0; nf < 4; ++nf) {
        float p = exp2_hw(sacc[nf][r] - mst[r]);
        sacc[nf][r] = p;
        rsum += p;
      }
      rsum += __shfl_xor(rsum, 1);
      rsum += __shfl_xor(rsum, 2);
      rsum += __shfl_xor(rsum, 4);
      rsum += __shfl_xor(rsum, 8);
      lst[r] += rsum;
    }

    // ---- P -> bf16 (cvt_pk) -> wave-private LDS rows (swizzled)
#pragma unroll
    for (int nf = 0; nf < 4; ++nf) {
      const int pcol2 = (nf * 16 + l15) * 2;
#pragma unroll
      for (int rp = 0; rp < 4; rp += 2) {
        u32 pk = cvtpk(sacc[nf][rp], sacc[nf][rp + 1]);
        int r0 = wrow + l4 * 4 + rp;
        int r1 = r0 + 1;
        *(u16*)(Ps + r0 * 128 + (pcol2 ^ ((r0 & 7) << 4))) = (u16)pk;
        *(u16*)(Ps + r1 * 128 + (pcol2 ^ ((r1 & 7) << 4))) = (u16)(pk >> 16);
      }
    }
    asm volatile("s_waitcnt lgkmcnt(0)" ::: "memory");

    // ---- O += P @ V
#pragma unroll
    for (int kvb = 0; kvb < 2; ++kvb) {
      const int cb = kvb * 64 + l4 * 16;
      short8 pf, vf[4];
      {
        int prow = wrow + l15;
        pf = *(const short8*)(Ps + prow * 128 + (cb ^ ((prow & 7) << 4)));
      }
#pragma unroll
      for (int nf = 0; nf < 4; ++nf) {
        int row = nf * 16 + l15;
        vf[nf] = *(const short8*)(Vs[cur] + row * 128 + (cb ^ ((row & 7) << 4)));
      }
#pragma unroll
      for (int nf = 0; nf < 4; ++nf)
        oacc[nf] = __builtin_amdgcn_mfma_f32_16x16x32_bf16(pf, vf[nf], oacc[nf], 0, 0, 0);
    }

    __syncthreads();  // drains vmcnt (next tile staged) + all waves done with cur
  }

  // epilogue: normalize and write context [B,S,D]
#pragma unroll
  for (int r = 0; r < 4; ++r) {
    float inv = 1.f / lst[r];
    int s = q0 + wrow + l4 * 4 + r;
#pragma unroll
    for (int nf = 0; nf < 4; ++nf) {
      int d = nf * 16 + l15;
      ctx[((long)(b * S_ + s)) * D_ + h * HD_ + d] = f2bf(oacc[nf][r] * inv);
    }
  }
}

// ---------------------------------------------------------------- LayerNorm (wave per row)
__global__ __launch_bounds__(256) void ln_kernel(
    const float* __restrict__ y, const float* __restrict__ gamma,
    const float* __restrict__ beta, float* __restrict__ out)
{
  const int lane = threadIdx.x & 63, wave = threadIdx.x >> 6;
  const long row = (long)blockIdx.x * 4 + wave;
  const float* yr = y + row * D_;
  f32x4 v0 = *(const f32x4*)&yr[lane * 8];
  f32x4 v1 = *(const f32x4*)&yr[lane * 8 + 4];
  float s = 0.f, ss = 0.f;
#pragma unroll
  for (int e = 0; e < 4; ++e) {
    s += v0[e]; ss += v0[e] * v0[e];
    s += v1[e]; ss += v1[e] * v1[e];
  }
#pragma unroll
  for (int msk = 1; msk < 64; msk <<= 1) {
    s += __shfl_xor(s, msk);
    ss += __shfl_xor(ss, msk);
  }
  float mean = s * (1.f / 512.f);
  float var = ss * (1.f / 512.f) - mean * mean;
  float inv = rsqrtf(var + 1e-5f);
  f32x4 g0 = *(const f32x4*)&gamma[lane * 8];
  f32x4 g1 = *(const f32x4*)&gamma[lane * 8 + 4];
  f32x4 b0 = *(const f32x4*)&beta[lane * 8];
  f32x4 b1 = *(const f32x4*)&beta[lane * 8 + 4];
  f32x4 o0, o1;
#pragma unroll
  for (int e = 0; e < 4; ++e) {
    o0[e] = (v0[e] - mean) * inv * g0[e] + b0[e];
    o1[e] = (v1[e] - mean) * inv * g1[e] + b1[e];
  }
  *(f32x4*)&out[row * D_ + lane * 8] = o0;
  *(f32x4*)&out[row * D_ + lane * 8 + 4] = o1;
}

// ---------------------------------------------------------------- launch
extern "C" void kernel_launch(void* const* d_in, const int* in_sizes, int n_in,
                              void* d_out, int out_size, void* d_ws, size_t ws_size,
                              hipStream_t stream) {
  const float* x  = (const float*)d_in[0];
  const float* Wq = (const float*)d_in[1];
  const float* bq = (const float*)d_in[2];
  const float* Wk = (const float*)d_in[3];
  const float* bk = (const float*)d_in[4];
  const float* Wv = (const float*)d_in[5];
  const float* bv = (const float*)d_in[6];
  const float* Wo = (const float*)d_in[7];
  const float* bo = (const float*)d_in[8];
  const float* lg = (const float*)d_in[9];
  const float* lb = (const float*)d_in[10];

  char* ws = (char*)d_ws;
  const size_t SZ_XB = (size_t)M_TOT * D_ * 2;  // 8 MiB per [M,D] bf16
  const size_t SZ_W  = (size_t)D_ * D_ * 2;
  u16* xb   = (u16*)(ws);
  u16* q_ws = (u16*)(ws + SZ_XB);
  u16* k_ws = (u16*)(ws + 2 * SZ_XB);
  u16* vt_ws= (u16*)(ws + 3 * SZ_XB);
  u16* c_ws = (u16*)(ws + 4 * SZ_XB);
  u16* wqb  = (u16*)(ws + 5 * SZ_XB);              // wq/wk/wv CONTIGUOUS: fused
  u16* wkb  = (u16*)(ws + 5 * SZ_XB + SZ_W);       //   GEMM indexes rows 0..1535
  u16* wvb  = (u16*)(ws + 5 * SZ_XB + 2 * SZ_W);
  u16* wob  = (u16*)(ws + 5 * SZ_XB + 3 * SZ_W);
  // y (fp32, 16 MiB) aliases xb+q_ws — both dead before out-proj writes it
  float* yf = (float*)(ws);

  cast_kernel<<<5120, 256, 0, stream>>>(x, Wq, Wk, Wv, Wo, xb, wqb, wkb, wvb, wob);

  // Fused QKV projection: N = 1536. Q scaled by (1/8)*log2(e) -> exp2-domain softmax.
  gemm_bt<<<dim3(M_TOT / BM, 1536 / BN), 256, 0, stream>>>(
      xb, wqb, bq, bk, bv, nullptr, q_ws, k_ws, vt_ws, nullptr,
      0.18033688011112042f, 0);

  attn_kernel<<<1024, 256, 0, stream>>>(q_ws, k_ws, vt_ws, c_ws);

  // Out-proj + bias + residual (fp32 out)
  gemm_bt<<<dim3(M_TOT / BM, D_ / BN), 256, 0, stream>>>(
      c_ws, wob, bo, nullptr, nullptr, x, nullptr, nullptr, nullptr, yf, 1.0f, 1);

  ln_kernel<<<M_TOT / 4, 256, 0, stream>>>(yf, lg, lb, (float*)d_out);
}

// Round 9
// 189.293 us; speedup vs baseline: 1.3304x; 1.3304x over previous
//
#include <hip/hip_runtime.h>
#include <hip/hip_bf16.h>

#define B_ 4
#define S_ 2048
#define D_ 512
#define H_ 8
#define HD_ 64
#define M_TOT 8192  // B_*S_

typedef __attribute__((ext_vector_type(8))) short short8;
typedef __attribute__((ext_vector_type(4))) float f32x4;
typedef __attribute__((ext_vector_type(16))) float f32x16;
typedef unsigned short u16;
typedef unsigned int u32;
typedef unsigned long long u64;

__device__ __forceinline__ u16 f2bf(float f) {
  union { float f; u32 u; } v; v.f = f;
  u32 u = v.u;
  return (u16)((u + 0x7fffu + ((u >> 16) & 1u)) >> 16);  // RNE
}

// HW packed f32->bf16 (RNE), lo = src0, hi = src1
__device__ __forceinline__ u32 cvtpk(float lo, float hi) {
  u32 r;
  asm("v_cvt_pk_bf16_f32 %0, %1, %2" : "=v"(r) : "v"(lo), "v"(hi));
  return r;
}

__device__ __forceinline__ float exp2_hw(float x) { return __builtin_amdgcn_exp2f(x); }

__device__ __forceinline__ void gload16(const void* g, void* l) {
  // width-16 global->LDS DMA; LDS dest = wave-uniform base + lane*16
  __builtin_amdgcn_global_load_lds(
      (const __attribute__((address_space(1))) unsigned int*)g,
      (__attribute__((address_space(3))) unsigned int*)l, 16, 0, 0);
}

// ---------------------------------------------------------------- cast to bf16
__global__ __launch_bounds__(256) void cast_kernel(
    const float* __restrict__ x, const float* __restrict__ wq, const float* __restrict__ wk,
    const float* __restrict__ wv, const float* __restrict__ wo,
    u16* __restrict__ xb, u16* __restrict__ wqb, u16* __restrict__ wkb,
    u16* __restrict__ wvb, u16* __restrict__ wob)
{
  const int NX = M_TOT * D_ / 4;  // 1048576 float4s
  const int NW = D_ * D_ / 4;     // 65536
  int i = blockIdx.x * 256 + threadIdx.x;
  const float* src; u16* dst; int o;
  if (i < NX)               { src = x;  dst = xb;  o = i; }
  else if (i < NX + NW)     { src = wq; dst = wqb; o = i - NX; }
  else if (i < NX + 2 * NW) { src = wk; dst = wkb; o = i - NX - NW; }
  else if (i < NX + 3 * NW) { src = wv; dst = wvb; o = i - NX - 2 * NW; }
  else if (i < NX + 4 * NW) { src = wo; dst = wob; o = i - NX - 3 * NW; }
  else return;
  f32x4 v = ((const f32x4*)src)[o];
  u32 p0 = (u32)f2bf(v[0]) | ((u32)f2bf(v[1]) << 16);
  u32 p1 = (u32)f2bf(v[2]) | ((u32)f2bf(v[3]) << 16);
  u32* d = (u32*)(dst + (long)o * 4);
  d[0] = p0; d[1] = p1;
}

// ---------------------------------------------------------------- bf16 GEMM, B^T weights
// C[m][n] = sum_k A[m][k]*Bw[n][k] (+bias)
// mode 0 (fused QKV, N=1536): n<512 -> Q (scaled 0.125*log2e) [bh][s][hd]
//                             n<1024 -> K [bh][s][hd]
//                             else   -> V TRANSPOSED [bh][hd][s], s-bits2<->3 swapped
//                                       (pi-relabel of the kv contraction axis so the
//                                        attn PV B-fragment is lane-local - see attn)
// mode 1 (out-proj, N=512): out_f32[m*D+n] = C + bias[n] + resid[m*D+n]
#define BM 128
#define BN 128
#define BKK 64

__global__ __launch_bounds__(256) void gemm_bt(
    const u16* __restrict__ A, const u16* __restrict__ Bw,
    const float* __restrict__ b0, const float* __restrict__ b1, const float* __restrict__ b2,
    const float* __restrict__ resid,
    u16* __restrict__ oq, u16* __restrict__ ok, u16* __restrict__ ov,
    float* __restrict__ out_f32, float qscale, int mode)
{
  __shared__ u16 As[BM * BKK];  // 16 KB, linear [row][128B] with XOR-swizzled contents
  __shared__ u16 Bs[BN * BKK];
  const int K = D_;
  const int tid = threadIdx.x;
  const int lane = tid & 63;
  const int wave = tid >> 6;
  const int wr = wave >> 1, wc = wave & 1;  // 2x2 waves, 64x64 each
  const int m0 = blockIdx.x * BM, n0 = blockIdx.y * BN;
  const int l15 = lane & 15, l4 = lane >> 4;

  f32x4 acc[4][4];
#pragma unroll
  for (int i = 0; i < 4; ++i)
#pragma unroll
    for (int j = 0; j < 4; ++j)
      acc[i][j] = (f32x4){0.f, 0.f, 0.f, 0.f};

  const int srow_in_grp = lane >> 3;            // 0..7
  const int schunk = (lane & 7) * 16;           // byte chunk within 128B row
  const int ssw = srow_in_grp << 4;             // row-XOR
  const char* Ab = (const char*)(A + (long)m0 * K);
  const char* Bb = (const char*)(Bw + (long)n0 * K);

  for (int k0 = 0; k0 < K; k0 += BKK) {
    __syncthreads();  // prior tile's frag reads done
#pragma unroll
    for (int i = 0; i < 4; ++i) {
      int row = (wave * 4 + i) * 8 + srow_in_grp;
      long gsrc = (long)row * (K * 2) + k0 * 2 + (schunk ^ ssw);
      gload16(Ab + gsrc, (char*)As + (wave * 4 + i) * 1024);
      gload16(Bb + gsrc, (char*)Bs + (wave * 4 + i) * 1024);
    }
    __syncthreads();  // drains vmcnt(0): tiles resident

#pragma unroll
    for (int kb = 0; kb < 2; ++kb) {
      short8 af[4], bf[4];
      const int cb = kb * 64 + l4 * 16;  // byte col within row
#pragma unroll
      for (int i = 0; i < 4; ++i) {
        int ra = wr * 64 + i * 16 + l15;
        int rb = wc * 64 + i * 16 + l15;
        af[i] = *(const short8*)((const char*)As + ra * 128 + (cb ^ ((ra & 7) << 4)));
        bf[i] = *(const short8*)((const char*)Bs + rb * 128 + (cb ^ ((rb & 7) << 4)));
      }
#pragma unroll
      for (int i = 0; i < 4; ++i)
#pragma unroll
        for (int j = 0; j < 4; ++j)
          acc[i][j] = __builtin_amdgcn_mfma_f32_16x16x32_bf16(af[i], bf[j], acc[i][j], 0, 0, 0);
    }
  }

  if (mode == 0) {
    const int which = n0 >> 9;  // block-uniform: 0=Q,1=K,2=V
    const float* bias = which == 0 ? b0 : (which == 1 ? b1 : b2);
    const float scale = which == 0 ? qscale : 1.0f;
    u16* outp = which == 0 ? oq : (which == 1 ? ok : ov);
#pragma unroll
    for (int i = 0; i < 4; ++i) {
#pragma unroll
      for (int j = 0; j < 4; ++j) {
        int n = n0 + wc * 64 + j * 16 + l15;
        int nn = n & 511;
        float bv = bias[nn];
        int h = nn >> 6, hd = nn & 63;
        int mbase = m0 + wr * 64 + i * 16 + l4 * 4;
        int b = mbase >> 11, s0 = mbase & 2047;
        if (which == 2) {
          // V^T: [bh][hd][s'] with s' = s bits2<->3 swapped (pi relabel, 8B store intact)
          int s0p = (s0 & ~12) | ((s0 & 4) << 1) | ((s0 & 8) >> 1);
          union { u16 u[4]; u64 ll; } pk;
#pragma unroll
          for (int r = 0; r < 4; ++r)
            pk.u[r] = f2bf(acc[i][j][r] + bv);
          *(u64*)&outp[((long)(b * H_ + h) * HD_ + hd) * S_ + s0p] = pk.ll;
        } else {
#pragma unroll
          for (int r = 0; r < 4; ++r) {
            float v = (acc[i][j][r] + bv) * scale;
            outp[((long)(b * H_ + h) * S_ + s0 + r) * HD_ + hd] = f2bf(v);
          }
        }
      }
    }
  } else {
#pragma unroll
    for (int i = 0; i < 4; ++i) {
#pragma unroll
      for (int j = 0; j < 4; ++j) {
        int n = n0 + wc * 64 + j * 16 + l15;
        float bv = b0[n];
#pragma unroll
        for (int r = 0; r < 4; ++r) {
          int m = m0 + wr * 64 + i * 16 + l4 * 4 + r;
          long idx = (long)m * D_ + n;
          out_f32[idx] = acc[i][j][r] + bv + resid[idx];
        }
      }
    }
  }
}

// ---------------------------------------------------------------- flash attention
// Swapped-operand 32x32x16 structure. Q pre-scaled by 0.125*log2e (exp2 softmax).
// P = mfma(K, Q): lane owns q = lane&31; kv over regs crow(reg)+4*(lane>>5)
//   (crow(r) = (r&3)+8*(r>>2), m74/m101-verified C/D).
// O = mfma(V, P): O's q is again lane-local -> rescale & 1/l need no cross-lane.
// PV B-frag (P) needs kv k-slots (lane>>5)*8+e; the GEMM stored V^T with kv
// bits2<->3 swapped so that lane-own P regs IN ORDER are exactly those slots:
//   pos(crow(ks*8+e)+4h, bits2<->3) = ks*16 + h*8 + e. Zero shuffles, no P LDS.
// 4 waves x 32 q-rows = 128 q/block; KV tile 64, double-buffered global_load_lds.
__global__ __launch_bounds__(256) void attn_kernel(
    const u16* __restrict__ Qg, const u16* __restrict__ Kg,
    const u16* __restrict__ Vtg, u16* __restrict__ ctx)
{
  __shared__ char Ks[2][8192];  // [kv 64][d 128B], XOR-swizzled contents
  __shared__ char Vs[2][8192];  // [d 64][kv 128B] (kv pi-permuted), XOR-swizzled

  const int tid = threadIdx.x, lane = tid & 63, wave = tid >> 6;
  const int l31 = lane & 31, lh = lane >> 5;
  const int lin = blockIdx.x;
  const int wg = (lin & 7) * 64 + (lin >> 3);  // XCD-chunked swizzle (512 = 8*64)
  const int bh = wg >> 4;                      // 16 q-tiles per (b,h)
  const int q0 = (wg & 15) * 128;
  const int b = bh >> 3, h = bh & 7;
  const long hoff = (long)bh * S_ * HD_;
  const u16* Qh = Qg + hoff;
  const char* Kb = (const char*)(Kg + hoff);
  const char* Vb = (const char*)(Vtg + hoff);
  const int qw = q0 + wave * 32;               // this wave's 32 q-rows

  // staging geometry (per lane): row-in-inst = lane>>3, 16B chunk = lane&7
  const int srow = lane >> 3;
  const int soff = ((lane & 7) * 16) ^ (srow << 4);  // pre-swizzled byte in 128B window

  // Q B-frags: lane: row q = qw+l31, d = dc*16 + lh*8 + e (held all sweep)
  short8 qf[4];
#pragma unroll
  for (int dc = 0; dc < 4; ++dc)
    qf[dc] = *(const short8*)&Qh[(long)(qw + l31) * HD_ + dc * 16 + lh * 8];

  float mrun = -1e30f, lrun = 0.f;
  f32x16 oacc[2];
#pragma unroll
  for (int db = 0; db < 2; ++db)
#pragma unroll
    for (int r = 0; r < 16; ++r) oacc[db][r] = 0.f;

  // ---- prologue: stage tile 0
#pragma unroll
  for (int j = 0; j < 2; ++j) {
    int r = wave * 16 + j * 8 + srow;
    gload16(Kb + (long)r * 128 + soff, Ks[0] + (wave * 2 + j) * 1024);
    gload16(Vb + (long)r * 4096 + soff, Vs[0] + (wave * 2 + j) * 1024);
  }
  __syncthreads();

  for (int t = 0; t < S_ / 64; ++t) {
    const int cur = t & 1;
    // ---- issue next tile's staging (in flight during compute)
    if (t < S_ / 64 - 1) {
      const int kv1 = (t + 1) * 64;
#pragma unroll
      for (int j = 0; j < 2; ++j) {
        int r = wave * 16 + j * 8 + srow;
        gload16(Kb + (long)(kv1 + r) * 128 + soff, Ks[cur ^ 1] + (wave * 2 + j) * 1024);
        gload16(Vb + (long)r * 4096 + (long)kv1 * 2 + soff, Vs[cur ^ 1] + (wave * 2 + j) * 1024);
      }
    }

    // ---- S^T = K @ Q^T : p[nt], lane q = l31, kv = nt*32 + crow(reg) + 4*lh
    f32x16 p0, p1;
    {
      f32x16 a0, a1;
#pragma unroll
      for (int r = 0; r < 16; ++r) { a0[r] = 0.f; a1[r] = 0.f; }
      const int swz = (l31 & 7) << 4;
#pragma unroll
      for (int dc = 0; dc < 4; ++dc) {
        const int cb = dc * 32 + lh * 16;
        short8 k0 = *(const short8*)(Ks[cur] + l31 * 128 + (cb ^ swz));
        short8 k1 = *(const short8*)(Ks[cur] + (32 + l31) * 128 + (cb ^ swz));
        a0 = __builtin_amdgcn_mfma_f32_32x32x16_bf16(k0, qf[dc], a0, 0, 0, 0);
        a1 = __builtin_amdgcn_mfma_f32_32x32x16_bf16(k1, qf[dc], a1, 0, 0, 0);
      }
      p0 = a0; p1 = a1;
    }

    // ---- online softmax (exp2 domain, defer-max THR=8); one m/l per lane (its q)
    float mt = p0[0];
#pragma unroll
    for (int r = 1; r < 16; ++r) mt = fmaxf(mt, p0[r]);
#pragma unroll
    for (int r = 0; r < 16; ++r) mt = fmaxf(mt, p1[r]);
    mt = fmaxf(mt, __shfl_xor(mt, 32));  // lanes l, l^32 hold complementary kv halves
    if (__any(mt > mrun + 8.0f)) {       // rare after warmup
      float mnew = fmaxf(mrun, mt);
      float rs = exp2_hw(mrun - mnew);
      mrun = mnew; lrun *= rs;
#pragma unroll
      for (int db = 0; db < 2; ++db)
#pragma unroll
        for (int r = 0; r < 16; ++r) oacc[db][r] *= rs;
    }
    float sum = 0.f;
#pragma unroll
    for (int r = 0; r < 16; ++r) { float v = exp2_hw(p0[r] - mrun); p0[r] = v; sum += v; }
#pragma unroll
    for (int r = 0; r < 16; ++r) { float v = exp2_hw(p1[r] - mrun); p1[r] = v; sum += v; }
    sum += __shfl_xor(sum, 32);
    lrun += sum;

    // ---- O += V @ P : P B-frag = own regs packed in order (pi-relabeled kv)
#pragma unroll
    for (int nt = 0; nt < 2; ++nt) {
#pragma unroll
      for (int ks = 0; ks < 2; ++ks) {
        union { u32 w[4]; short8 s; } pa;
        const f32x16& pp = nt ? p1 : p0;
        pa.w[0] = cvtpk(pp[ks * 8 + 0], pp[ks * 8 + 1]);
        pa.w[1] = cvtpk(pp[ks * 8 + 2], pp[ks * 8 + 3]);
        pa.w[2] = cvtpk(pp[ks * 8 + 4], pp[ks * 8 + 5]);
        pa.w[3] = cvtpk(pp[ks * 8 + 6], pp[ks * 8 + 7]);
        const int colb = nt * 64 + ks * 32 + lh * 16;
#pragma unroll
        for (int db = 0; db < 2; ++db) {
          const int vr = db * 32 + l31;
          short8 vf = *(const short8*)(Vs[cur] + vr * 128 + (colb ^ ((vr & 7) << 4)));
          oacc[db] = __builtin_amdgcn_mfma_f32_32x32x16_bf16(vf, pa.s, oacc[db], 0, 0, 0);
        }
      }
    }

    __syncthreads();  // drains vmcnt (next tile staged) + all waves done with cur
  }

  // epilogue: O[q][d]: q = qw+l31 (lane-local), d = db*32 + crow(reg) + 4*lh
  const float inv = 1.f / lrun;
  u16* crow0 = ctx + (long)(b * S_ + (qw + l31)) * D_ + h * HD_;
#pragma unroll
  for (int db = 0; db < 2; ++db) {
#pragma unroll
    for (int rq = 0; rq < 4; ++rq) {
      const int d0 = db * 32 + rq * 8 + lh * 4;  // regs 4rq..4rq+3 -> d0..d0+3
      u32 lo = cvtpk(oacc[db][rq * 4 + 0] * inv, oacc[db][rq * 4 + 1] * inv);
      u32 hi = cvtpk(oacc[db][rq * 4 + 2] * inv, oacc[db][rq * 4 + 3] * inv);
      *(u64*)(crow0 + d0) = (u64)lo | ((u64)hi << 32);
    }
  }
}

// ---------------------------------------------------------------- LayerNorm (wave per row)
__global__ __launch_bounds__(256) void ln_kernel(
    const float* __restrict__ y, const float* __restrict__ gamma,
    const float* __restrict__ beta, float* __restrict__ out)
{
  const int lane = threadIdx.x & 63, wave = threadIdx.x >> 6;
  const long row = (long)blockIdx.x * 4 + wave;
  const float* yr = y + row * D_;
  f32x4 v0 = *(const f32x4*)&yr[lane * 8];
  f32x4 v1 = *(const f32x4*)&yr[lane * 8 + 4];
  float s = 0.f, ss = 0.f;
#pragma unroll
  for (int e = 0; e < 4; ++e) {
    s += v0[e]; ss += v0[e] * v0[e];
    s += v1[e]; ss += v1[e] * v1[e];
  }
#pragma unroll
  for (int msk = 1; msk < 64; msk <<= 1) {
    s += __shfl_xor(s, msk);
    ss += __shfl_xor(ss, msk);
  }
  float mean = s * (1.f / 512.f);
  float var = ss * (1.f / 512.f) - mean * mean;
  float inv = rsqrtf(var + 1e-5f);
  f32x4 g0 = *(const f32x4*)&gamma[lane * 8];
  f32x4 g1 = *(const f32x4*)&gamma[lane * 8 + 4];
  f32x4 b0 = *(const f32x4*)&beta[lane * 8];
  f32x4 b1 = *(const f32x4*)&beta[lane * 8 + 4];
  f32x4 o0, o1;
#pragma unroll
  for (int e = 0; e < 4; ++e) {
    o0[e] = (v0[e] - mean) * inv * g0[e] + b0[e];
    o1[e] = (v1[e] - mean) * inv * g1[e] + b1[e];
  }
  *(f32x4*)&out[row * D_ + lane * 8] = o0;
  *(f32x4*)&out[row * D_ + lane * 8 + 4] = o1;
}

// ---------------------------------------------------------------- launch
extern "C" void kernel_launch(void* const* d_in, const int* in_sizes, int n_in,
                              void* d_out, int out_size, void* d_ws, size_t ws_size,
                              hipStream_t stream) {
  const float* x  = (const float*)d_in[0];
  const float* Wq = (const float*)d_in[1];
  const float* bq = (const float*)d_in[2];
  const float* Wk = (const float*)d_in[3];
  const float* bk = (const float*)d_in[4];
  const float* Wv = (const float*)d_in[5];
  const float* bv = (const float*)d_in[6];
  const float* Wo = (const float*)d_in[7];
  const float* bo = (const float*)d_in[8];
  const float* lg = (const float*)d_in[9];
  const float* lb = (const float*)d_in[10];

  char* ws = (char*)d_ws;
  const size_t SZ_XB = (size_t)M_TOT * D_ * 2;  // 8 MiB per [M,D] bf16
  const size_t SZ_W  = (size_t)D_ * D_ * 2;
  u16* xb   = (u16*)(ws);
  u16* q_ws = (u16*)(ws + SZ_XB);
  u16* k_ws = (u16*)(ws + 2 * SZ_XB);
  u16* vt_ws= (u16*)(ws + 3 * SZ_XB);
  u16* c_ws = (u16*)(ws + 4 * SZ_XB);
  u16* wqb  = (u16*)(ws + 5 * SZ_XB);              // wq/wk/wv CONTIGUOUS: fused
  u16* wkb  = (u16*)(ws + 5 * SZ_XB + SZ_W);       //   GEMM indexes rows 0..1535
  u16* wvb  = (u16*)(ws + 5 * SZ_XB + 2 * SZ_W);
  u16* wob  = (u16*)(ws + 5 * SZ_XB + 3 * SZ_W);
  // y (fp32, 16 MiB) aliases xb+q_ws — both dead before out-proj writes it
  float* yf = (float*)(ws);

  cast_kernel<<<5120, 256, 0, stream>>>(x, Wq, Wk, Wv, Wo, xb, wqb, wkb, wvb, wob);

  // Fused QKV projection: N = 1536. Q scaled by (1/8)*log2(e) -> exp2-domain softmax.
  gemm_bt<<<dim3(M_TOT / BM, 1536 / BN), 256, 0, stream>>>(
      xb, wqb, bq, bk, bv, nullptr, q_ws, k_ws, vt_ws, nullptr,
      0.18033688011112042f, 0);

  attn_kernel<<<512, 256, 0, stream>>>(q_ws, k_ws, vt_ws, c_ws);

  // Out-proj + bias + residual (fp32 out)
  gemm_bt<<<dim3(M_TOT / BM, D_ / BN), 256, 0, stream>>>(
      c_ws, wob, bo, nullptr, nullptr, x, nullptr, nullptr, nullptr, yf, 1.0f, 1);

  ln_kernel<<<M_TOT / 4, 256, 0, stream>>>(yf, lg, lb, (float*)d_out);
}